// Round 8
// baseline (255.817 us; speedup 1.0000x reference)
//
#include <hip/hip_runtime.h>
#include <hip/hip_bf16.h>
#include <math.h>

#define NPOS 32768      // 32*32*32
#define CCH  128
#define C3   384
#define CF   512

typedef __attribute__((ext_vector_type(8))) short short8;
typedef __attribute__((ext_vector_type(4))) float f32x4;

__device__ inline float bf2f(unsigned short u) {
    union { unsigned int i; float f; } x; x.i = ((unsigned int)u) << 16; return x.f;
}
__device__ inline unsigned short f2bf(float f) {
    union { float f; unsigned int i; } x; x.f = f;
    unsigned int r = x.i + 0x7FFFu + ((x.i >> 16) & 1u);   // round-nearest-even
    return (unsigned short)(r >> 16);
}
__device__ inline float lo_bf(unsigned int u) {
    union { unsigned int i; float f; } x; x.i = u << 16; return x.f;
}
__device__ inline float hi_bf(unsigned int u) {
    union { unsigned int i; float f; } x; x.i = u & 0xffff0000u; return x.f;
}

// ---------------------------------------------------------------------------
// bf16 MFMA GEMM, swapped-operand epilogue (lane holds 4 consecutive cols).
// Tile MT x NT, BK=32, 256 thr = 4 waves (WM x WN, WM=MT/64).
// STATS: epilogue also emits per-block channel sum/sumsq partials
//        (requires grid.x==1 and Nout==NT==128, WM==1).
// ---------------------------------------------------------------------------
template<int MT, int NT, bool GELU, bool RES, bool WF32, bool WBF, bool STATS>
__global__ __launch_bounds__(256) void gemm_mfma(
    const unsigned short* __restrict__ A, const unsigned short* __restrict__ B,
    const float* __restrict__ bias, const unsigned short* __restrict__ res,
    float* __restrict__ outf, unsigned short* __restrict__ outb,
    float* __restrict__ partials,
    int M, int Nout, int K)
{
    constexpr int WM  = MT / 64;        // wave rows (1 or 2)
    constexpr int WN  = 4 / WM;         // wave cols
    constexpr int NT2 = NT / WN;        // per-wave n extent
    constexpr int NJW = NT2 / 16;       // n fragments per wave

    __shared__ alignas(16) unsigned short As[MT * 40];
    __shared__ alignas(16) unsigned short Bs[NT * 40];

    const int tid  = threadIdx.x;
    const int lane = tid & 63;
    const int wave = tid >> 6;
    const int wm = wave % WM, wn = wave / WM;
    const int row0 = blockIdx.y * MT;
    const int col0 = blockIdx.x * NT;

    const f32x4 fzero = {0.f, 0.f, 0.f, 0.f};
    f32x4 acc[4][NJW];
    #pragma unroll
    for (int i = 0; i < 4; ++i)
        #pragma unroll
        for (int j = 0; j < NJW; ++j) acc[i][j] = fzero;

    const int lr   = lane & 15;
    const int quad = lane >> 4;
    const int lk   = quad * 8;

    for (int kt = 0; kt < K; kt += 32) {
        #pragma unroll
        for (int c = tid; c < (MT + NT) * 4; c += 256) {
            const int r = c >> 2;
            const int p = (c & 3) * 8;
            if (r < MT) {
                *(uint4*)&As[r * 40 + p] =
                    *(const uint4*)&A[(size_t)(row0 + r) * K + kt + p];
            } else {
                const int rb = r - MT;
                *(uint4*)&Bs[rb * 40 + p] =
                    *(const uint4*)&B[(size_t)(col0 + rb) * K + kt + p];
            }
        }
        __syncthreads();
        short8 af[4], bfr[NJW];
        #pragma unroll
        for (int i = 0; i < 4; ++i)
            af[i]  = *(const short8*)&As[(wm * 64 + i * 16 + lr) * 40 + lk];
        #pragma unroll
        for (int j = 0; j < NJW; ++j)
            bfr[j] = *(const short8*)&Bs[(wn * NT2 + j * 16 + lr) * 40 + lk];
        #pragma unroll
        for (int i = 0; i < 4; ++i)
            #pragma unroll
            for (int j = 0; j < NJW; ++j)
                acc[i][j] = __builtin_amdgcn_mfma_f32_16x16x32_bf16(
                                bfr[j], af[i], acc[i][j], 0, 0, 0);
        __syncthreads();
    }

    // Swapped C layout: m = row0+wm*64+i*16+lr, n = col0+wn*NT2+j*16+quad*4+r
    float4 bias4[NJW];
    #pragma unroll
    for (int j = 0; j < NJW; ++j)
        bias4[j] = *(const float4*)&bias[col0 + wn * NT2 + j * 16 + quad * 4];

    float ssum[NJW][4], ssq[NJW][4];
    if (STATS) {
        #pragma unroll
        for (int j = 0; j < NJW; ++j)
            #pragma unroll
            for (int r = 0; r < 4; ++r) { ssum[j][r] = 0.f; ssq[j][r] = 0.f; }
    }

    #pragma unroll
    for (int i = 0; i < 4; ++i) {
        const int m = row0 + wm * 64 + i * 16 + lr;
        #pragma unroll
        for (int j = 0; j < NJW; ++j) {
            const int n0 = col0 + wn * NT2 + j * 16 + quad * 4;
            float v[4];
            #pragma unroll
            for (int r = 0; r < 4; ++r) {
                v[r] = acc[i][j][r] + (&bias4[j].x)[r];
                if (GELU) {
                    const float g = 0.7978845608028654f *
                        (v[r] + 0.044715f * v[r] * v[r] * v[r]);
                    const float e = __expf(2.f * g);
                    v[r] = v[r] * (e / (e + 1.f));
                }
            }
            if (RES) {
                const ushort4 rv = *(const ushort4*)&res[(size_t)m * Nout + n0];
                v[0] += bf2f(rv.x); v[1] += bf2f(rv.y);
                v[2] += bf2f(rv.z); v[3] += bf2f(rv.w);
            }
            if (STATS) {
                #pragma unroll
                for (int r = 0; r < 4; ++r) {
                    ssum[j][r] += v[r];
                    ssq[j][r]  += v[r] * v[r];
                }
            }
            if (WF32) {
                float4 o; o.x = v[0]; o.y = v[1]; o.z = v[2]; o.w = v[3];
                *(float4*)&outf[(size_t)m * Nout + n0] = o;
            }
            if (WBF) {
                ushort4 o;
                o.x = f2bf(v[0]); o.y = f2bf(v[1]); o.z = f2bf(v[2]); o.w = f2bf(v[3]);
                *(ushort4*)&outb[(size_t)m * Nout + n0] = o;
            }
        }
    }

    if (STATS) {
        // reduce over the 16 m-lanes (lr); quad preserved by masks 1,2,4,8
        #pragma unroll
        for (int j = 0; j < NJW; ++j) {
            #pragma unroll
            for (int r = 0; r < 4; ++r) {
                float s = ssum[j][r], q = ssq[j][r];
                #pragma unroll
                for (int mask = 1; mask <= 8; mask <<= 1) {
                    s += __shfl_xor(s, mask);
                    q += __shfl_xor(q, mask);
                }
                if (lr == 0) {
                    const int n = wn * NT2 + j * 16 + quad * 4 + r;
                    partials[(size_t)blockIdx.y * 256 + n]       = s;
                    partials[(size_t)blockIdx.y * 256 + 128 + n] = q;
                }
            }
        }
    }
}

// ---------------------------------------------------------------------------
// Tiled neighborhood attention (unchanged)
// ---------------------------------------------------------------------------
__global__ __launch_bounds__(256) void attn_tiled(
    const unsigned short* __restrict__ qkv, const float* __restrict__ rpb,
    unsigned short* __restrict__ out)
{
    __shared__ unsigned int ksu[288 * 8];
    __shared__ unsigned int vsu[288 * 8];
    __shared__ unsigned int qsu[32 * 8];
    __shared__ float logits[32 * 29];
    __shared__ float rpbs[125];

    const int t  = threadIdx.x;
    const int line = ((blockIdx.x & 7) << 7) + (blockIdx.x >> 3);
    const int h  = blockIdx.y;
    const int w0 = line & 31, h0 = line >> 5;
    const int n0 = (h0 << 10) + (w0 << 5);
    const int sh0 = min(max(h0 - 1, 0), 29);
    const int sw0 = min(max(w0 - 1, 0), 29);
    const int rh_off = sh0 - h0 + 2;
    const int rw_off = sw0 - w0 + 2;

    if (t < 64) {
        const int pos = t >> 1, part = t & 1;
        const uint4 raw = *(const uint4*)&qkv[(size_t)(n0 + pos) * C3 + h * 16 + part * 8];
        *(uint4*)&qsu[pos * 8 + part * 4] = raw;
    } else if (t < 192) {
        const int i = t - 64;
        if (i < 125) rpbs[i] = rpb[h * 125 + i];
    }
    for (int c = t; c < 1152; c += 256) {
        const int p = c >> 2, part = c & 3;
        const int ihw = p >> 5, z = p & 31;
        const int ih = (ihw * 11) >> 5;
        const int iw = ihw - 3 * ih;
        const int n = ((sh0 + ih) << 10) + ((sw0 + iw) << 5) + z;
        const uint4 raw = *(const uint4*)&qkv[(size_t)n * C3 + CCH + (part >> 1) * CCH
                                              + h * 16 + (part & 1) * 8];
        unsigned int* d = ((part < 2) ? ksu : vsu) + p * 8 + (part & 1) * 4;
        *(uint4*)d = raw;
    }
    __syncthreads();

    {
        const int q = t >> 3, j = t & 7;
        const int sz = min(max(q - 1, 0), 29);
        const int rz_off = sz - q + 2;
        float qf[16];
        #pragma unroll
        for (int d2 = 0; d2 < 8; ++d2) {
            const unsigned int u = qsu[q * 8 + d2];
            qf[2 * d2] = lo_bf(u); qf[2 * d2 + 1] = hi_bf(u);
        }
        for (int kk = j; kk < 27; kk += 8) {
            const int ihw = kk / 3, dz = kk - 3 * ihw;
            const int ih = ihw / 3,  iw = ihw - 3 * ih;
            const int p = ihw * 32 + sz + dz;
            float a = 0.f;
            #pragma unroll
            for (int d2 = 0; d2 < 8; ++d2) {
                const unsigned int u = ksu[p * 8 + d2];
                a += qf[2 * d2] * lo_bf(u) + qf[2 * d2 + 1] * hi_bf(u);
            }
            const int bidx = ((ih + rh_off) * 5 + (iw + rw_off)) * 5 + (dz + rz_off);
            logits[q * 29 + kk] = a * 0.25f + rpbs[bidx];
        }
    }
    __syncthreads();

    if (t < 32) {
        float mx = -1e30f;
        #pragma unroll
        for (int kk = 0; kk < 27; ++kk) mx = fmaxf(mx, logits[t * 29 + kk]);
        float s = 0.f;
        #pragma unroll
        for (int kk = 0; kk < 27; ++kk) {
            const float e = __expf(logits[t * 29 + kk] - mx);
            logits[t * 29 + kk] = e; s += e;
        }
        const float inv = 1.f / s;
        #pragma unroll
        for (int kk = 0; kk < 27; ++kk) logits[t * 29 + kk] *= inv;
    }
    __syncthreads();

    {
        const int q = t >> 3, d2 = t & 7;
        const int sz = min(max(q - 1, 0), 29);
        float ax = 0.f, ay = 0.f;
        #pragma unroll
        for (int kk = 0; kk < 27; ++kk) {
            const int p = (kk / 3) * 32 + sz + (kk % 3);
            const float w = logits[q * 29 + kk];
            const unsigned int u = vsu[p * 8 + d2];
            ax += w * lo_bf(u); ay += w * hi_bf(u);
        }
        const unsigned int o = ((unsigned int)f2bf(ay) << 16) | (unsigned int)f2bf(ax);
        *(unsigned int*)&out[(size_t)(n0 + q) * CCH + h * 16 + d2 * 2] = o;
    }
}

// reduce 512 partial rows -> stats[256]
__global__ __launch_bounds__(256) void stats_p2(
    const float* __restrict__ partials, float* __restrict__ stats)
{
    const int t = threadIdx.x;
    float s = 0.f;
    #pragma unroll 8
    for (int b = 0; b < 512; ++b) s += partials[b * 256 + t];
    stats[t] = s;
}

// normalize (N,128) fp32 -> bf16 (reads stats sums)
__global__ __launch_bounds__(256) void norm_apply_bf(
    const float* __restrict__ a, const float* __restrict__ stats,
    unsigned short* __restrict__ o)
{
    const int i = blockIdx.x * 256 + threadIdx.x;
    const int c0 = (i * 4) & (CCH - 1);
    const float4 v = ((const float4*)a)[i];
    const float invN = 1.f / (float)NPOS;
    ushort4 r;
    #pragma unroll
    for (int j = 0; j < 4; ++j) {
        const int c = c0 + j;
        const float m = stats[c] * invN;
        const float var = stats[CCH + c] * invN - m * m;
        const float rs = rsqrtf(var + 1e-5f);
        (&r.x)[j] = f2bf(((&v.x)[j] - m) * rs);
    }
    *(ushort4*)&o[(size_t)i * 4] = r;
}

// fused: zero stats + convert all four weight matrices fp32->bf16
__global__ __launch_bounds__(256) void prep_kernel(
    const float* __restrict__ wq, const float* __restrict__ wp,
    const float* __restrict__ w1, const float* __restrict__ w2,
    unsigned short* __restrict__ wq_b, unsigned short* __restrict__ wp_b,
    unsigned short* __restrict__ w1_b, unsigned short* __restrict__ w2_b,
    float* __restrict__ stats)
{
    const int i = blockIdx.x * 256 + threadIdx.x;
    if (blockIdx.x == 0) {
        stats[threadIdx.x] = 0.f;
        stats[threadIdx.x + 256] = 0.f;
    }
    const float* src; unsigned short* dst; int off;
    if (i < 12288)      { src = wq; dst = wq_b; off = i; }
    else if (i < 16384) { src = wp; dst = wp_b; off = i - 12288; }
    else if (i < 32768) { src = w1; dst = w1_b; off = i - 16384; }
    else                { src = w2; dst = w2_b; off = i - 32768; }
    const float4 v = ((const float4*)src)[off];
    ushort4 o;
    o.x = f2bf(v.x); o.y = f2bf(v.y); o.z = f2bf(v.z); o.w = f2bf(v.w);
    ((ushort4*)dst)[off] = o;
}

// normalize + transpose (N,C) fp32 -> (C,N) fp32 output
__global__ void norm_transpose_kernel(
    const float* __restrict__ t, const float* __restrict__ stats,
    float* __restrict__ out)
{
    __shared__ float tile[32][33];
    const int n0 = blockIdx.x * 32;
    const int c0 = blockIdx.y * 32;
    const int tx = threadIdx.x;
    const int ty = threadIdx.y;
    for (int i = ty; i < 32; i += 8)
        tile[i][tx] = t[(size_t)(n0 + i) * CCH + c0 + tx];
    __syncthreads();
    const float invN = 1.f / (float)NPOS;
    for (int i = ty; i < 32; i += 8) {
        const int c = c0 + i;
        const float m = stats[c] * invN;
        const float var = stats[CCH + c] * invN - m * m;
        const float rs = rsqrtf(var + 1e-5f);
        out[(size_t)c * NPOS + n0 + tx] = (tile[tx][i] - m) * rs;
    }
}

// transpose x (C,N) fp32 -> (N,C) bf16
__global__ __launch_bounds__(256) void transpose_x_kernel(
    const float* __restrict__ x, unsigned short* __restrict__ xt)
{
    __shared__ float tile[32][33];
    const int n0 = blockIdx.x * 32;
    const int c0 = blockIdx.y * 32;
    const int tx = threadIdx.x & 31;
    const int ty = threadIdx.x >> 5;
    for (int i = ty; i < 32; i += 8)
        tile[i][tx] = x[(size_t)(c0 + i) * NPOS + n0 + tx];
    __syncthreads();
    for (int i = ty; i < 32; i += 8)
        xt[(size_t)(n0 + i) * CCH + c0 + tx] = f2bf(tile[tx][i]);
}

// ---------------------------------------------------------------------------
extern "C" void kernel_launch(void* const* d_in, const int* in_sizes, int n_in,
                              void* d_out, int out_size, void* d_ws, size_t ws_size,
                              hipStream_t stream)
{
    const float* x      = (const float*)d_in[0];   // (128, 32768) = (C, N)
    const float* w_qkv  = (const float*)d_in[1];
    const float* b_qkv  = (const float*)d_in[2];
    const float* rpb    = (const float*)d_in[3];
    const float* w_proj = (const float*)d_in[4];
    const float* b_proj = (const float*)d_in[5];
    const float* w_ffn1 = (const float*)d_in[6];
    const float* b_ffn1 = (const float*)d_in[7];
    const float* w_ffn2 = (const float*)d_in[8];
    const float* b_ffn2 = (const float*)d_in[9];
    float* out = (float*)d_out;

    char* ws = (char*)d_ws;
    unsigned short* xt_bf    = (unsigned short*)(ws + 0);          // 8.39 MB
    unsigned short* qkv_bf   = (unsigned short*)(ws + 8388608);    // 25.2 MB
    unsigned short* ffn1_bf  = (unsigned short*)(ws + 0);          // 33.6 MB (reuse)
    unsigned short* attnO_bf = (unsigned short*)(ws + 33554432);   // 8.39 MB
    float*          x5       = (float*)(ws + 41943040);            // 16.8 MB
    unsigned short* x5n_bf   = (unsigned short*)(ws + 58720256);   // 8.39 MB
    float*          tbuf     = (float*)(ws + 67108864);            // 16.8 MB
    unsigned short* wqkv_bf  = (unsigned short*)(ws + 83886080);
    unsigned short* wproj_bf = (unsigned short*)(ws + 83984384);
    unsigned short* wffn1_bf = (unsigned short*)(ws + 84017152);
    unsigned short* wffn2_bf = (unsigned short*)(ws + 84148224);
    float*          stats    = (float*)(ws + 84279296);            // 512 floats
    float*          partials = (float*)(ws + 84283392);            // 512 KB
    float* stats1 = stats;
    float* stats2 = stats + 256;

    // 0) fused prep + transpose-convert x
    prep_kernel<<<192, 256, 0, stream>>>(w_qkv, w_proj, w_ffn1, w_ffn2,
                                         wqkv_bf, wproj_bf, wffn1_bf, wffn2_bf, stats);
    transpose_x_kernel<<<dim3(NPOS / 32, CCH / 32), 256, 0, stream>>>(x, xt_bf);

    // 1) qkv = xt @ w_qkv^T + b_qkv   (bf16 out; 64x128 tiles)
    gemm_mfma<64, 128, false, false, false, true, false>
        <<<dim3(C3 / 128, NPOS / 64), 256, 0, stream>>>(
        xt_bf, wqkv_bf, b_qkv, nullptr, nullptr, qkv_bf, nullptr, NPOS, C3, CCH);

    // 2) tiled neighborhood attention
    attn_tiled<<<dim3(1024, 8), 256, 0, stream>>>(qkv_bf, rpb, attnO_bf);

    // 3) x5 = attnO @ w_proj^T + b_proj  (fp32 out + fused stats partials)
    gemm_mfma<64, 128, false, false, true, false, true>
        <<<dim3(1, NPOS / 64), 256, 0, stream>>>(
        attnO_bf, wproj_bf, b_proj, nullptr, x5, nullptr, partials, NPOS, CCH, CCH);

    // 4) finish instance norm #1 stats, materialize normalized bf16
    stats_p2<<<1, 256, 0, stream>>>(partials, stats1);
    norm_apply_bf<<<(NPOS * CCH / 4) / 256, 256, 0, stream>>>(x5, stats1, x5n_bf);

    // 5) ffn1 = gelu(x5n @ w_ffn1^T + b_ffn1)  (bf16 out)
    gemm_mfma<64, 128, true, false, false, true, false>
        <<<dim3(CF / 128, NPOS / 64), 256, 0, stream>>>(
        x5n_bf, wffn1_bf, b_ffn1, nullptr, nullptr, ffn1_bf, nullptr, NPOS, CF, CCH);

    // 6) t = x5n + ffn1 @ w_ffn2^T + b_ffn2  (fp32 out + fused stats partials)
    gemm_mfma<64, 128, false, true, true, false, true>
        <<<dim3(1, NPOS / 64), 256, 0, stream>>>(
        ffn1_bf, wffn2_bf, b_ffn2, x5n_bf, tbuf, nullptr, partials, NPOS, CCH, CF);

    // 7) finish instance norm #2 stats + transpose to (C,N)
    stats_p2<<<1, 256, 0, stream>>>(partials, stats2);
    norm_transpose_kernel<<<dim3(NPOS / 32, CCH / 32), dim3(32, 8), 0, stream>>>(
        tbuf, stats2, out);
}

// Round 9
// 236.818 us; speedup vs baseline: 1.0802x; 1.0802x over previous
//
#include <hip/hip_runtime.h>
#include <hip/hip_bf16.h>
#include <math.h>

#define NPOS 32768      // 32*32*32
#define CCH  128
#define C3   384
#define CF   512

typedef __attribute__((ext_vector_type(8))) short short8;
typedef __attribute__((ext_vector_type(4))) float f32x4;

__device__ inline float bf2f(unsigned short u) {
    union { unsigned int i; float f; } x; x.i = ((unsigned int)u) << 16; return x.f;
}
__device__ inline unsigned short f2bf(float f) {
    union { float f; unsigned int i; } x; x.f = f;
    unsigned int r = x.i + 0x7FFFu + ((x.i >> 16) & 1u);   // round-nearest-even
    return (unsigned short)(r >> 16);
}
__device__ inline float lo_bf(unsigned int u) {
    union { unsigned int i; float f; } x; x.i = u << 16; return x.f;
}
__device__ inline float hi_bf(unsigned int u) {
    union { unsigned int i; float f; } x; x.i = u & 0xffff0000u; return x.f;
}
__device__ inline float gelu_f(float v) {
    const float g = 0.7978845608028654f * (v + 0.044715f * v * v * v);
    const float e = __expf(2.f * g);
    return v * (e / (e + 1.f));
}

// ---------------------------------------------------------------------------
// bf16 MFMA GEMM, swapped-operand epilogue (lane holds 4 consecutive cols).
// Tile MT x NT, BK=32, 256 thr = 4 waves (WM x WN, WM=MT/64).
// STATS: epilogue emits per-block channel sum/sumsq partials (grid.x==1,
// Nout==NT==128, WM==1).
// ---------------------------------------------------------------------------
template<int MT, int NT, bool GELU, bool RES, bool WF32, bool WBF, bool STATS>
__global__ __launch_bounds__(256) void gemm_mfma(
    const unsigned short* __restrict__ A, const unsigned short* __restrict__ B,
    const float* __restrict__ bias, const unsigned short* __restrict__ res,
    float* __restrict__ outf, unsigned short* __restrict__ outb,
    float* __restrict__ partials,
    int M, int Nout, int K)
{
    constexpr int WM  = MT / 64;
    constexpr int WN  = 4 / WM;
    constexpr int NT2 = NT / WN;
    constexpr int NJW = NT2 / 16;

    __shared__ alignas(16) unsigned short As[MT * 40];
    __shared__ alignas(16) unsigned short Bs[NT * 40];

    const int tid  = threadIdx.x;
    const int lane = tid & 63;
    const int wave = tid >> 6;
    const int wm = wave % WM, wn = wave / WM;
    const int row0 = blockIdx.y * MT;
    const int col0 = blockIdx.x * NT;

    const f32x4 fzero = {0.f, 0.f, 0.f, 0.f};
    f32x4 acc[4][NJW];
    #pragma unroll
    for (int i = 0; i < 4; ++i)
        #pragma unroll
        for (int j = 0; j < NJW; ++j) acc[i][j] = fzero;

    const int lr   = lane & 15;
    const int quad = lane >> 4;
    const int lk   = quad * 8;

    for (int kt = 0; kt < K; kt += 32) {
        #pragma unroll
        for (int c = tid; c < (MT + NT) * 4; c += 256) {
            const int r = c >> 2;
            const int p = (c & 3) * 8;
            if (r < MT) {
                *(uint4*)&As[r * 40 + p] =
                    *(const uint4*)&A[(size_t)(row0 + r) * K + kt + p];
            } else {
                const int rb = r - MT;
                *(uint4*)&Bs[rb * 40 + p] =
                    *(const uint4*)&B[(size_t)(col0 + rb) * K + kt + p];
            }
        }
        __syncthreads();
        short8 af[4], bfr[NJW];
        #pragma unroll
        for (int i = 0; i < 4; ++i)
            af[i]  = *(const short8*)&As[(wm * 64 + i * 16 + lr) * 40 + lk];
        #pragma unroll
        for (int j = 0; j < NJW; ++j)
            bfr[j] = *(const short8*)&Bs[(wn * NT2 + j * 16 + lr) * 40 + lk];
        #pragma unroll
        for (int i = 0; i < 4; ++i)
            #pragma unroll
            for (int j = 0; j < NJW; ++j)
                acc[i][j] = __builtin_amdgcn_mfma_f32_16x16x32_bf16(
                                bfr[j], af[i], acc[i][j], 0, 0, 0);
        __syncthreads();
    }

    float4 bias4[NJW];
    #pragma unroll
    for (int j = 0; j < NJW; ++j)
        bias4[j] = *(const float4*)&bias[col0 + wn * NT2 + j * 16 + quad * 4];

    float ssum[NJW][4], ssq[NJW][4];
    if (STATS) {
        #pragma unroll
        for (int j = 0; j < NJW; ++j)
            #pragma unroll
            for (int r = 0; r < 4; ++r) { ssum[j][r] = 0.f; ssq[j][r] = 0.f; }
    }

    #pragma unroll
    for (int i = 0; i < 4; ++i) {
        const int m = row0 + wm * 64 + i * 16 + lr;
        #pragma unroll
        for (int j = 0; j < NJW; ++j) {
            const int n0 = col0 + wn * NT2 + j * 16 + quad * 4;
            float v[4];
            #pragma unroll
            for (int r = 0; r < 4; ++r) {
                v[r] = acc[i][j][r] + (&bias4[j].x)[r];
                if (GELU) v[r] = gelu_f(v[r]);
            }
            if (RES) {
                const ushort4 rv = *(const ushort4*)&res[(size_t)m * Nout + n0];
                v[0] += bf2f(rv.x); v[1] += bf2f(rv.y);
                v[2] += bf2f(rv.z); v[3] += bf2f(rv.w);
            }
            if (STATS) {
                #pragma unroll
                for (int r = 0; r < 4; ++r) {
                    ssum[j][r] += v[r];
                    ssq[j][r]  += v[r] * v[r];
                }
            }
            if (WF32) {
                float4 o; o.x = v[0]; o.y = v[1]; o.z = v[2]; o.w = v[3];
                *(float4*)&outf[(size_t)m * Nout + n0] = o;
            }
            if (WBF) {
                ushort4 o;
                o.x = f2bf(v[0]); o.y = f2bf(v[1]); o.z = f2bf(v[2]); o.w = f2bf(v[3]);
                *(ushort4*)&outb[(size_t)m * Nout + n0] = o;
            }
        }
    }

    if (STATS) {
        #pragma unroll
        for (int j = 0; j < NJW; ++j) {
            #pragma unroll
            for (int r = 0; r < 4; ++r) {
                float s = ssum[j][r], q = ssq[j][r];
                #pragma unroll
                for (int mask = 1; mask <= 8; mask <<= 1) {
                    s += __shfl_xor(s, mask);
                    q += __shfl_xor(q, mask);
                }
                if (lr == 0) {
                    const int n = wn * NT2 + j * 16 + quad * 4 + r;
                    partials[(size_t)blockIdx.y * 256 + n]       = s;
                    partials[(size_t)blockIdx.y * 256 + 128 + n] = q;
                }
            }
        }
    }
}

// ---------------------------------------------------------------------------
// Fused FFN: t = x5n + gelu(x5n @ W1^T + b1) @ W2^T + b2, x5n = norm(x5_bf).
// One block = 64 positions, full 512-hidden via 4 chunks of 128.
// Xs (normalized input) and Hs (gelu output) live in LDS; weights staged in
// 32-wide K slices. Emits fp32 out + fused stats partials.
// ---------------------------------------------------------------------------
__global__ __launch_bounds__(256) void fused_ffn(
    const unsigned short* __restrict__ x5bf, const unsigned short* __restrict__ w1,
    const float* __restrict__ b1, const unsigned short* __restrict__ w2,
    const float* __restrict__ b2, const float* __restrict__ stats,
    float* __restrict__ outf, float* __restrict__ partials)
{
    __shared__ alignas(16) unsigned short Xs[64 * 136];   // 272B row stride (16B mult)
    __shared__ alignas(16) unsigned short Hs[64 * 136];
    __shared__ alignas(16) unsigned short Ws[128 * 40];
    __shared__ float mLDS[128], rsLDS[128];

    const int tid  = threadIdx.x;
    const int lane = tid & 63;
    const int wave = tid >> 6;       // 0..3 = n-group
    const int lr   = lane & 15;
    const int quad = lane >> 4;
    const int lk   = quad * 8;
    const int row0 = blockIdx.x * 64;

    if (tid < 128) {
        const float invN = 1.f / (float)NPOS;
        const float m = stats[tid] * invN;
        const float var = stats[128 + tid] * invN - m * m;
        mLDS[tid] = m;
        rsLDS[tid] = rsqrtf(var + 1e-5f);
    }
    __syncthreads();

    // stage Xs = normalized bf16 tile (64 x 128)
    #pragma unroll
    for (int c = tid; c < 1024; c += 256) {
        const int r = c >> 4;
        const int p = (c & 15) * 8;
        const uint4 raw = *(const uint4*)&x5bf[(size_t)(row0 + r) * CCH + p];
        const unsigned short* s = (const unsigned short*)&raw;
        ushort4 o0, o1;
        #pragma unroll
        for (int e = 0; e < 4; ++e) {
            (&o0.x)[e] = f2bf((bf2f(s[e])     - mLDS[p + e])     * rsLDS[p + e]);
            (&o1.x)[e] = f2bf((bf2f(s[4 + e]) - mLDS[p + 4 + e]) * rsLDS[p + 4 + e]);
        }
        *(ushort4*)&Xs[r * 136 + p]     = o0;
        *(ushort4*)&Xs[r * 136 + p + 4] = o1;
    }

    const f32x4 fzero = {0.f, 0.f, 0.f, 0.f};
    f32x4 oacc[4][2];
    #pragma unroll
    for (int i = 0; i < 4; ++i)
        #pragma unroll
        for (int j = 0; j < 2; ++j) oacc[i][j] = fzero;

    for (int ch = 0; ch < 4; ++ch) {
        f32x4 hacc[4][2];
        #pragma unroll
        for (int i = 0; i < 4; ++i)
            #pragma unroll
            for (int j = 0; j < 2; ++j) hacc[i][j] = fzero;

        // ---- GEMM1: H = Xs @ W1c^T (K = 128)
        for (int kt = 0; kt < 128; kt += 32) {
            __syncthreads();                       // Ws free (and Xs staged, 1st iter)
            #pragma unroll
            for (int c = tid; c < 512; c += 256) {
                const int r = c >> 2, p = (c & 3) * 8;
                *(uint4*)&Ws[r * 40 + p] =
                    *(const uint4*)&w1[(size_t)(ch * 128 + r) * CCH + kt + p];
            }
            __syncthreads();
            short8 af[4], bfr[2];
            #pragma unroll
            for (int i = 0; i < 4; ++i)
                af[i] = *(const short8*)&Xs[(i * 16 + lr) * 136 + kt + lk];
            #pragma unroll
            for (int j = 0; j < 2; ++j)
                bfr[j] = *(const short8*)&Ws[(wave * 32 + j * 16 + lr) * 40 + lk];
            #pragma unroll
            for (int i = 0; i < 4; ++i)
                #pragma unroll
                for (int j = 0; j < 2; ++j)
                    hacc[i][j] = __builtin_amdgcn_mfma_f32_16x16x32_bf16(
                                     bfr[j], af[i], hacc[i][j], 0, 0, 0);
        }

        // ---- GELU epilogue -> Hs (bf16). Barriers of next loop order wrt reads.
        float4 b1v[2];
        #pragma unroll
        for (int j = 0; j < 2; ++j)
            b1v[j] = *(const float4*)&b1[ch * 128 + wave * 32 + j * 16 + quad * 4];
        #pragma unroll
        for (int i = 0; i < 4; ++i) {
            const int m = i * 16 + lr;
            #pragma unroll
            for (int j = 0; j < 2; ++j) {
                const int n0 = wave * 32 + j * 16 + quad * 4;
                ushort4 o;
                #pragma unroll
                for (int r = 0; r < 4; ++r)
                    (&o.x)[r] = f2bf(gelu_f(hacc[i][j][r] + (&b1v[j].x)[r]));
                *(ushort4*)&Hs[m * 136 + n0] = o;
            }
        }

        // ---- GEMM2: O += H @ W2c^T (K = 128 of this chunk)
        for (int kt = 0; kt < 128; kt += 32) {
            __syncthreads();                       // Hs written, Ws free
            #pragma unroll
            for (int c = tid; c < 512; c += 256) {
                const int r = c >> 2, p = (c & 3) * 8;
                *(uint4*)&Ws[r * 40 + p] =
                    *(const uint4*)&w2[(size_t)r * CF + ch * 128 + kt + p];
            }
            __syncthreads();
            short8 af[4], bfr[2];
            #pragma unroll
            for (int i = 0; i < 4; ++i)
                af[i] = *(const short8*)&Hs[(i * 16 + lr) * 136 + kt + lk];
            #pragma unroll
            for (int j = 0; j < 2; ++j)
                bfr[j] = *(const short8*)&Ws[(wave * 32 + j * 16 + lr) * 40 + lk];
            #pragma unroll
            for (int i = 0; i < 4; ++i)
                #pragma unroll
                for (int j = 0; j < 2; ++j)
                    oacc[i][j] = __builtin_amdgcn_mfma_f32_16x16x32_bf16(
                                     bfr[j], af[i], oacc[i][j], 0, 0, 0);
        }
    }

    // ---- final epilogue: bias2 + residual(Xs) + fp32 write + stats partials
    float4 b2v[2];
    #pragma unroll
    for (int j = 0; j < 2; ++j)
        b2v[j] = *(const float4*)&b2[wave * 32 + j * 16 + quad * 4];

    float ssum[2][4], ssq[2][4];
    #pragma unroll
    for (int j = 0; j < 2; ++j)
        #pragma unroll
        for (int r = 0; r < 4; ++r) { ssum[j][r] = 0.f; ssq[j][r] = 0.f; }

    #pragma unroll
    for (int i = 0; i < 4; ++i) {
        const int m = i * 16 + lr;
        #pragma unroll
        for (int j = 0; j < 2; ++j) {
            const int n0 = wave * 32 + j * 16 + quad * 4;
            const ushort4 rv = *(const ushort4*)&Xs[m * 136 + n0];
            float v[4];
            v[0] = oacc[i][j][0] + (&b2v[j].x)[0] + bf2f(rv.x);
            v[1] = oacc[i][j][1] + (&b2v[j].x)[1] + bf2f(rv.y);
            v[2] = oacc[i][j][2] + (&b2v[j].x)[2] + bf2f(rv.z);
            v[3] = oacc[i][j][3] + (&b2v[j].x)[3] + bf2f(rv.w);
            #pragma unroll
            for (int r = 0; r < 4; ++r) {
                ssum[j][r] += v[r];
                ssq[j][r]  += v[r] * v[r];
            }
            float4 o; o.x = v[0]; o.y = v[1]; o.z = v[2]; o.w = v[3];
            *(float4*)&outf[(size_t)(row0 + m) * CCH + n0] = o;
        }
    }
    #pragma unroll
    for (int j = 0; j < 2; ++j) {
        #pragma unroll
        for (int r = 0; r < 4; ++r) {
            float s = ssum[j][r], q = ssq[j][r];
            #pragma unroll
            for (int mask = 1; mask <= 8; mask <<= 1) {
                s += __shfl_xor(s, mask);
                q += __shfl_xor(q, mask);
            }
            if (lr == 0) {
                const int n = wave * 32 + j * 16 + quad * 4 + r;
                partials[(size_t)blockIdx.x * 256 + n]       = s;
                partials[(size_t)blockIdx.x * 256 + 128 + n] = q;
            }
        }
    }
}

// ---------------------------------------------------------------------------
// Tiled neighborhood attention (unchanged)
// ---------------------------------------------------------------------------
__global__ __launch_bounds__(256) void attn_tiled(
    const unsigned short* __restrict__ qkv, const float* __restrict__ rpb,
    unsigned short* __restrict__ out)
{
    __shared__ unsigned int ksu[288 * 8];
    __shared__ unsigned int vsu[288 * 8];
    __shared__ unsigned int qsu[32 * 8];
    __shared__ float logits[32 * 29];
    __shared__ float rpbs[125];

    const int t  = threadIdx.x;
    const int line = ((blockIdx.x & 7) << 7) + (blockIdx.x >> 3);
    const int h  = blockIdx.y;
    const int w0 = line & 31, h0 = line >> 5;
    const int n0 = (h0 << 10) + (w0 << 5);
    const int sh0 = min(max(h0 - 1, 0), 29);
    const int sw0 = min(max(w0 - 1, 0), 29);
    const int rh_off = sh0 - h0 + 2;
    const int rw_off = sw0 - w0 + 2;

    if (t < 64) {
        const int pos = t >> 1, part = t & 1;
        const uint4 raw = *(const uint4*)&qkv[(size_t)(n0 + pos) * C3 + h * 16 + part * 8];
        *(uint4*)&qsu[pos * 8 + part * 4] = raw;
    } else if (t < 192) {
        const int i = t - 64;
        if (i < 125) rpbs[i] = rpb[h * 125 + i];
    }
    for (int c = t; c < 1152; c += 256) {
        const int p = c >> 2, part = c & 3;
        const int ihw = p >> 5, z = p & 31;
        const int ih = (ihw * 11) >> 5;
        const int iw = ihw - 3 * ih;
        const int n = ((sh0 + ih) << 10) + ((sw0 + iw) << 5) + z;
        const uint4 raw = *(const uint4*)&qkv[(size_t)n * C3 + CCH + (part >> 1) * CCH
                                              + h * 16 + (part & 1) * 8];
        unsigned int* d = ((part < 2) ? ksu : vsu) + p * 8 + (part & 1) * 4;
        *(uint4*)d = raw;
    }
    __syncthreads();

    {
        const int q = t >> 3, j = t & 7;
        const int sz = min(max(q - 1, 0), 29);
        const int rz_off = sz - q + 2;
        float qf[16];
        #pragma unroll
        for (int d2 = 0; d2 < 8; ++d2) {
            const unsigned int u = qsu[q * 8 + d2];
            qf[2 * d2] = lo_bf(u); qf[2 * d2 + 1] = hi_bf(u);
        }
        for (int kk = j; kk < 27; kk += 8) {
            const int ihw = kk / 3, dz = kk - 3 * ihw;
            const int ih = ihw / 3,  iw = ihw - 3 * ih;
            const int p = ihw * 32 + sz + dz;
            float a = 0.f;
            #pragma unroll
            for (int d2 = 0; d2 < 8; ++d2) {
                const unsigned int u = ksu[p * 8 + d2];
                a += qf[2 * d2] * lo_bf(u) + qf[2 * d2 + 1] * hi_bf(u);
            }
            const int bidx = ((ih + rh_off) * 5 + (iw + rw_off)) * 5 + (dz + rz_off);
            logits[q * 29 + kk] = a * 0.25f + rpbs[bidx];
        }
    }
    __syncthreads();

    if (t < 32) {
        float mx = -1e30f;
        #pragma unroll
        for (int kk = 0; kk < 27; ++kk) mx = fmaxf(mx, logits[t * 29 + kk]);
        float s = 0.f;
        #pragma unroll
        for (int kk = 0; kk < 27; ++kk) {
            const float e = __expf(logits[t * 29 + kk] - mx);
            logits[t * 29 + kk] = e; s += e;
        }
        const float inv = 1.f / s;
        #pragma unroll
        for (int kk = 0; kk < 27; ++kk) logits[t * 29 + kk] *= inv;
    }
    __syncthreads();

    {
        const int q = t >> 3, d2 = t & 7;
        const int sz = min(max(q - 1, 0), 29);
        float ax = 0.f, ay = 0.f;
        #pragma unroll
        for (int kk = 0; kk < 27; ++kk) {
            const int p = (kk / 3) * 32 + sz + (kk % 3);
            const float w = logits[q * 29 + kk];
            const unsigned int u = vsu[p * 8 + d2];
            ax += w * lo_bf(u); ay += w * hi_bf(u);
        }
        const unsigned int o = ((unsigned int)f2bf(ay) << 16) | (unsigned int)f2bf(ax);
        *(unsigned int*)&out[(size_t)(n0 + q) * CCH + h * 16 + d2 * 2] = o;
    }
}

// reduce 512 partial rows -> stats[256]
__global__ __launch_bounds__(256) void stats_p2(
    const float* __restrict__ partials, float* __restrict__ stats)
{
    const int t = threadIdx.x;
    float s = 0.f;
    #pragma unroll 8
    for (int b = 0; b < 512; ++b) s += partials[b * 256 + t];
    stats[t] = s;
}

// fused: zero stats + convert all four weight matrices fp32->bf16
__global__ __launch_bounds__(256) void prep_kernel(
    const float* __restrict__ wq, const float* __restrict__ wp,
    const float* __restrict__ w1, const float* __restrict__ w2,
    unsigned short* __restrict__ wq_b, unsigned short* __restrict__ wp_b,
    unsigned short* __restrict__ w1_b, unsigned short* __restrict__ w2_b,
    float* __restrict__ stats)
{
    const int i = blockIdx.x * 256 + threadIdx.x;
    if (blockIdx.x == 0) {
        stats[threadIdx.x] = 0.f;
        stats[threadIdx.x + 256] = 0.f;
    }
    const float* src; unsigned short* dst; int off;
    if (i < 12288)      { src = wq; dst = wq_b; off = i; }
    else if (i < 16384) { src = wp; dst = wp_b; off = i - 12288; }
    else if (i < 32768) { src = w1; dst = w1_b; off = i - 16384; }
    else                { src = w2; dst = w2_b; off = i - 32768; }
    const float4 v = ((const float4*)src)[off];
    ushort4 o;
    o.x = f2bf(v.x); o.y = f2bf(v.y); o.z = f2bf(v.z); o.w = f2bf(v.w);
    ((ushort4*)dst)[off] = o;
}

// normalize + transpose (N,C) fp32 -> (C,N) fp32 output
__global__ void norm_transpose_kernel(
    const float* __restrict__ t, const float* __restrict__ stats,
    float* __restrict__ out)
{
    __shared__ float tile[32][33];
    const int n0 = blockIdx.x * 32;
    const int c0 = blockIdx.y * 32;
    const int tx = threadIdx.x;
    const int ty = threadIdx.y;
    for (int i = ty; i < 32; i += 8)
        tile[i][tx] = t[(size_t)(n0 + i) * CCH + c0 + tx];
    __syncthreads();
    const float invN = 1.f / (float)NPOS;
    for (int i = ty; i < 32; i += 8) {
        const int c = c0 + i;
        const float m = stats[c] * invN;
        const float var = stats[CCH + c] * invN - m * m;
        const float rs = rsqrtf(var + 1e-5f);
        out[(size_t)c * NPOS + n0 + tx] = (tile[tx][i] - m) * rs;
    }
}

// transpose x (C,N) fp32 -> (N,C) bf16
__global__ __launch_bounds__(256) void transpose_x_kernel(
    const float* __restrict__ x, unsigned short* __restrict__ xt)
{
    __shared__ float tile[32][33];
    const int n0 = blockIdx.x * 32;
    const int c0 = blockIdx.y * 32;
    const int tx = threadIdx.x & 31;
    const int ty = threadIdx.x >> 5;
    for (int i = ty; i < 32; i += 8)
        tile[i][tx] = x[(size_t)(c0 + i) * NPOS + n0 + tx];
    __syncthreads();
    for (int i = ty; i < 32; i += 8)
        xt[(size_t)(n0 + i) * CCH + c0 + tx] = f2bf(tile[tx][i]);
}

// ---------------------------------------------------------------------------
extern "C" void kernel_launch(void* const* d_in, const int* in_sizes, int n_in,
                              void* d_out, int out_size, void* d_ws, size_t ws_size,
                              hipStream_t stream)
{
    const float* x      = (const float*)d_in[0];   // (128, 32768) = (C, N)
    const float* w_qkv  = (const float*)d_in[1];
    const float* b_qkv  = (const float*)d_in[2];
    const float* rpb    = (const float*)d_in[3];
    const float* w_proj = (const float*)d_in[4];
    const float* b_proj = (const float*)d_in[5];
    const float* w_ffn1 = (const float*)d_in[6];
    const float* b_ffn1 = (const float*)d_in[7];
    const float* w_ffn2 = (const float*)d_in[8];
    const float* b_ffn2 = (const float*)d_in[9];
    float* out = (float*)d_out;

    char* ws = (char*)d_ws;
    unsigned short* xt_bf    = (unsigned short*)(ws + 0);          // 8.39 MB
    unsigned short* qkv_bf   = (unsigned short*)(ws + 8388608);    // 25.2 MB
    unsigned short* attnO_bf = (unsigned short*)(ws + 33554432);   // 8.39 MB
    unsigned short* x5_bf    = (unsigned short*)(ws + 58720256);   // 8.39 MB
    float*          tbuf     = (float*)(ws + 67108864);            // 16.8 MB
    unsigned short* wqkv_bf  = (unsigned short*)(ws + 83886080);
    unsigned short* wproj_bf = (unsigned short*)(ws + 83984384);
    unsigned short* wffn1_bf = (unsigned short*)(ws + 84017152);
    unsigned short* wffn2_bf = (unsigned short*)(ws + 84148224);
    float*          stats    = (float*)(ws + 84279296);            // 512 floats
    float*          partials = (float*)(ws + 84283392);            // 512 KB
    float* stats1 = stats;
    float* stats2 = stats + 256;

    // 0) fused prep + transpose-convert x
    prep_kernel<<<192, 256, 0, stream>>>(w_qkv, w_proj, w_ffn1, w_ffn2,
                                         wqkv_bf, wproj_bf, wffn1_bf, wffn2_bf, stats);
    transpose_x_kernel<<<dim3(NPOS / 32, CCH / 32), 256, 0, stream>>>(x, xt_bf);

    // 1) qkv = xt @ w_qkv^T + b_qkv   (bf16 out; 64x128 tiles)
    gemm_mfma<64, 128, false, false, false, true, false>
        <<<dim3(C3 / 128, NPOS / 64), 256, 0, stream>>>(
        xt_bf, wqkv_bf, b_qkv, nullptr, nullptr, qkv_bf, nullptr, NPOS, C3, CCH);

    // 2) tiled neighborhood attention
    attn_tiled<<<dim3(1024, 8), 256, 0, stream>>>(qkv_bf, rpb, attnO_bf);

    // 3) x5_bf = attnO @ w_proj^T + b_proj  (bf16 out + fused stats partials)
    gemm_mfma<64, 128, false, false, false, true, true>
        <<<dim3(1, NPOS / 64), 256, 0, stream>>>(
        attnO_bf, wproj_bf, b_proj, nullptr, nullptr, x5_bf, partials, NPOS, CCH, CCH);

    // 4) finish instance norm #1 stats
    stats_p2<<<1, 256, 0, stream>>>(partials, stats1);

    // 5+6) fused FFN: tbuf = norm(x5) + gelu(norm(x5)@W1^T+b1)@W2^T + b2
    //      (+ fused stats2 partials)
    fused_ffn<<<NPOS / 64, 256, 0, stream>>>(
        x5_bf, wffn1_bf, b_ffn1, wffn2_bf, b_ffn2, stats1, tbuf, partials);

    // 7) finish instance norm #2 stats + transpose to (C,N)
    stats_p2<<<1, 256, 0, stream>>>(partials, stats2);
    norm_transpose_kernel<<<dim3(NPOS / 32, CCH / 32), dim3(32, 8), 0, stream>>>(
        tbuf, stats2, out);
}